// Round 1
// baseline (98.652 us; speedup 1.0000x reference)
//
#include <hip/hip_runtime.h>
#include <hip/hip_bf16.h>

// Problem constants
constexpr int B = 8, N = 2048, J = 4, F = 16, C = 2;
constexpr int MS = 16;          // m-splits (reduction parallelism)
constexpr int MC = N / MS;      // 128 m per chunk
constexpr int TN = 256;         // n-tile == block size
constexpr int NT = N / TN;      // 8 n-tiles

// out[b,c,n] = sum_m sum_j W[b,m,n,j] * t[c,j,m] + cb[c]
//   t[c,j,m]  = sum_f cw[c, j*F+f] * x[b,f,m]
__global__ __launch_bounds__(256) void gnn_fused_kernel(
    const float* __restrict__ W,   // [B,N,N,J]
    const float* __restrict__ x,   // [B,F,N]
    const float* __restrict__ cw,  // [C, J*F]
    const float* __restrict__ cb,  // [C]
    float* __restrict__ out)       // [B,N,C]
{
    __shared__ float t[MC][8];        // [m_local][c*4 + j]
    __shared__ float s_cw[C * J * F]; // 128 floats

    const int tid = threadIdx.x;
    const int blk = blockIdx.x;          // ((b*NT)+ntile)*MS + mchunk
    const int mchunk = blk % MS;
    const int tmp    = blk / MS;
    const int ntile  = tmp % NT;
    const int b      = tmp / NT;
    const int m0 = mchunk * MC;
    const int n0 = ntile * TN;

    if (tid < C * J * F) s_cw[tid] = cw[tid];
    __syncthreads();

    // threads 0..127: compute t[m][c*4+j] for this m-chunk
    if (tid < MC) {
        const int m = m0 + tid;
        const float* xb = x + (size_t)b * F * N + m;
        float xv[F];
#pragma unroll
        for (int f = 0; f < F; ++f) xv[f] = xb[(size_t)f * N];
#pragma unroll
        for (int c = 0; c < C; ++c) {
#pragma unroll
            for (int j = 0; j < J; ++j) {
                float s = 0.f;
#pragma unroll
                for (int f = 0; f < F; ++f) s += s_cw[c * (J * F) + j * F + f] * xv[f];
                t[tid][c * 4 + j] = s;
            }
        }
    }
    __syncthreads();

    // main streaming loop: each thread owns n = n0 + tid
    const int n = n0 + tid;
    const float4* Wp = (const float4*)(W + (((size_t)b * N + m0) * N + n) * J);
    const size_t mstride = (size_t)N * J / 4;  // float4 stride between m's

    float acc0 = 0.f, acc1 = 0.f;
#pragma unroll 4
    for (int mi = 0; mi < MC; ++mi) {
        float4 w4 = Wp[(size_t)mi * mstride];
        const float4* tv = (const float4*)t[mi];   // broadcast LDS reads
        float4 t0 = tv[0];   // c=0, j=0..3
        float4 t1 = tv[1];   // c=1, j=0..3
        acc0 += w4.x * t0.x + w4.y * t0.y + w4.z * t0.z + w4.w * t0.w;
        acc1 += w4.x * t1.x + w4.y * t1.y + w4.z * t1.z + w4.w * t1.w;
    }

    if (mchunk == 0) { acc0 += cb[0]; acc1 += cb[1]; }

    float* o = out + ((size_t)b * N + n) * C;
    atomicAdd(o,     acc0);
    atomicAdd(o + 1, acc1);
}

extern "C" void kernel_launch(void* const* d_in, const int* in_sizes, int n_in,
                              void* d_out, int out_size, void* d_ws, size_t ws_size,
                              hipStream_t stream) {
    const float* W  = (const float*)d_in[0];
    const float* x  = (const float*)d_in[1];
    const float* cw = (const float*)d_in[2];
    const float* cb = (const float*)d_in[3];
    float* out = (float*)d_out;

    // zero output (harness poisons once; atomics accumulate into it)
    hipMemsetAsync(out, 0, (size_t)out_size * sizeof(float), stream);

    dim3 grid(B * NT * MS);
    dim3 block(TN);
    gnn_fused_kernel<<<grid, block, 0, stream>>>(W, x, cw, cb, out);
}